// Round 1
// baseline (196.743 us; speedup 1.0000x reference)
//
#include <hip/hip_runtime.h>

using u16 = unsigned short;
using u32 = unsigned int;

typedef __bf16 bf16x8 __attribute__((ext_vector_type(8)));
typedef float  f32x4  __attribute__((ext_vector_type(4)));
typedef u16    u16x8  __attribute__((ext_vector_type(8)));
typedef u32    u32x4  __attribute__((ext_vector_type(4)));
typedef float  f32x4v __attribute__((ext_vector_type(4)));

// fp32 -> bf16 bits, round-to-nearest-even
__device__ __forceinline__ u32 f2bf(float f) {
  u32 u = __builtin_bit_cast(u32, f);
  return (u + 0x7fffu + ((u >> 16) & 1u)) >> 16;
}

// async global->LDS, 16B per lane; LDS dest is wave-uniform base + lane*16
__device__ __forceinline__ void gload_lds16(const u16* g, u16* lds) {
  __builtin_amdgcn_global_load_lds(
      (const __attribute__((address_space(1))) void*)g,
      (__attribute__((address_space(3))) void*)lds, 16, 0, 0);
}

// ---------------------------------------------------------------------------
// fp32 -> bf16 conversion of x (4194304) + Wq/Wk/Wv/Wo (4 x 1048576),
// written contiguously at ws[0 .. 8388608)
// ---------------------------------------------------------------------------
__global__ __launch_bounds__(256) void cvt_all(
    const float* __restrict__ x,  const float* __restrict__ wq,
    const float* __restrict__ wk, const float* __restrict__ wv,
    const float* __restrict__ wo, u16* __restrict__ out) {
  size_t i = ((size_t)blockIdx.x * 256 + threadIdx.x) * 8;
  const float* src;
  if (i < 4194304) {
    src = x + i;
  } else {
    size_t j = i - 4194304;
    unsigned w = (unsigned)(j >> 20);
    size_t o = j & 1048575;
    src = (w == 0) ? (wq + o) : (w == 1) ? (wk + o) : (w == 2) ? (wv + o) : (wo + o);
  }
  f32x4 a = *(const f32x4*)src;
  f32x4 b = *(const f32x4*)(src + 4);
  u32x4 r;
  r[0] = f2bf(a[0]) | (f2bf(a[1]) << 16);
  r[1] = f2bf(a[2]) | (f2bf(a[3]) << 16);
  r[2] = f2bf(b[0]) | (f2bf(b[1]) << 16);
  r[3] = f2bf(b[2]) | (f2bf(b[3]) << 16);
  *(u32x4*)(out + i) = r;
}

// ---------------------------------------------------------------------------
// C[M,N] = A[M,K] * B[N,K]^T, bf16 in, fp32 accum. 128x128 tile, BK=64,
// 4 waves each computing 64x64 via 4x4 frags of 16x16x32 MFMA.
// LDS tiles [128 rows][64 cols] with 16B-chunk XOR swizzle (key = row&7),
// staged via global_load_lds with pre-swizzled global source (rule #21).
// K = ldc = lda = ldb = 1024 hardcoded.
// ---------------------------------------------------------------------------
template <bool F32OUT>
__device__ __forceinline__ void gemm_tile(const u16* __restrict__ A,
                                          const u16* __restrict__ Bm,
                                          void* __restrict__ Cv,
                                          int rowBase, int colBase) {
  __shared__ __align__(16) u16 As[128 * 64];
  __shared__ __align__(16) u16 Bs[128 * 64];

  const int t = threadIdx.x;
  const int lane = t & 63;
  const int wv = t >> 6;
  const int wr = (wv >> 1) * 64;
  const int wc = (wv & 1) * 64;
  const int l15 = lane & 15;
  const int lg = lane >> 4;

  f32x4 acc[4][4] = {};

  for (int kt = 0; kt < 1024; kt += 64) {
#pragma unroll
    for (int i = 0; i < 4; ++i) {
      int s = i * 256 + t;
      int row = s >> 3;
      int k2 = (s & 7) ^ (row & 7);  // source-side swizzle
      const u16* ga = A  + (size_t)(rowBase + row) * 1024 + kt + k2 * 8;
      const u16* gb = Bm + (size_t)(colBase + row) * 1024 + kt + k2 * 8;
      gload_lds16(ga, &As[(i * 256 + wv * 64) * 8]);
      gload_lds16(gb, &Bs[(i * 256 + wv * 64) * 8]);
    }
    __syncthreads();
#pragma unroll
    for (int kk = 0; kk < 2; ++kk) {
      bf16x8 af[4], bfr[4];
#pragma unroll
      for (int m = 0; m < 4; ++m) {
        int row = wr + m * 16 + l15;
        af[m] = *(const bf16x8*)&As[row * 64 + (((kk * 4 + lg) ^ (row & 7)) * 8)];
      }
#pragma unroll
      for (int n = 0; n < 4; ++n) {
        int row = wc + n * 16 + l15;
        bfr[n] = *(const bf16x8*)&Bs[row * 64 + (((kk * 4 + lg) ^ (row & 7)) * 8)];
      }
#pragma unroll
      for (int m = 0; m < 4; ++m)
#pragma unroll
        for (int n = 0; n < 4; ++n)
          acc[m][n] = __builtin_amdgcn_mfma_f32_16x16x32_bf16(af[m], bfr[n], acc[m][n], 0, 0, 0);
    }
    __syncthreads();
  }

  // epilogue: D layout col = lane&15, row = (lane>>4)*4 + r
#pragma unroll
  for (int m = 0; m < 4; ++m) {
#pragma unroll
    for (int r = 0; r < 4; ++r) {
      int row = rowBase + wr + m * 16 + lg * 4 + r;
#pragma unroll
      for (int n = 0; n < 4; ++n) {
        int col = colBase + wc + n * 16 + l15;
        float v = acc[m][n][r];
        if (F32OUT)
          ((float*)Cv)[(size_t)row * 1024 + col] = v;
        else
          ((u16*)Cv)[(size_t)row * 1024 + col] = (u16)f2bf(v);
      }
    }
  }
}

__global__ __launch_bounds__(256) void gemm_qkv(
    const u16* __restrict__ xb,
    const u16* __restrict__ wq, const u16* __restrict__ wk, const u16* __restrict__ wv,
    u16* __restrict__ Qm, u16* __restrict__ Km, u16* __restrict__ Vm) {
  int bx = blockIdx.x;
  int mat = bx >> 8;      // 0:Q 1:K 2:V
  int rem = bx & 255;
  int bm = rem & 31, bn = rem >> 5;
  const u16* B = (mat == 0) ? wq : (mat == 1) ? wk : wv;
  u16* C = (mat == 0) ? Qm : (mat == 1) ? Km : Vm;
  gemm_tile<false>(xb, B, C, bm * 128, bn * 128);
}

__global__ __launch_bounds__(256) void gemm_out(
    const u16* __restrict__ ao, const u16* __restrict__ wo, float* __restrict__ C) {
  int bm = blockIdx.x & 31, bn = blockIdx.x >> 5;
  gemm_tile<true>(ao, wo, C, bm * 128, bn * 128);
}

// ---------------------------------------------------------------------------
// Flash attention. Q,K,V are bf16 [4096][1024]; head (b,h) at row b*2048,
// col h*64, row stride 1024. Block = 4 waves, each wave owns 32 q rows
// (QBLK=128). KVBLK=64, 32 KV tiles. Scale 1/8 folded into exp2.
// ---------------------------------------------------------------------------
__global__ __launch_bounds__(256) void attn_fwd(
    const u16* __restrict__ Q, const u16* __restrict__ K,
    const u16* __restrict__ V, u16* __restrict__ AO) {
  __shared__ __align__(16) u16 Ks[64 * 64];
  __shared__ __align__(16) u16 Vt[64 * 64];       // transposed: [d][kv], swizzled
  __shared__ __align__(16) u16 Pl[4][32 * 64];    // per-wave P, swizzled

  const int t = threadIdx.x;
  const int lane = t & 63;
  const int wv = t >> 6;
  const int l15 = lane & 15;
  const int lg = lane >> 4;

  const int qb = blockIdx.x;          // 0..15
  const int pr = blockIdx.y;          // 0..31
  const int b = pr >> 4, h = pr & 15;
  const size_t hb = (size_t)b * 2048 * 1024 + (size_t)h * 64;
  const u16* Qh = Q + hb;
  const u16* Kh = K + hb;
  const u16* Vh = V + hb;
  u16* AOh = AO + hb;

  const int q0 = qb * 128 + wv * 32;

  // hoist Q frags: A-operand lane layout row=l&15, k=8*(l>>4)+e
  bf16x8 qf[2][2];
#pragma unroll
  for (int m = 0; m < 2; ++m)
#pragma unroll
    for (int kk = 0; kk < 2; ++kk)
      qf[m][kk] = *(const bf16x8*)&Qh[(size_t)(q0 + m * 16 + l15) * 1024 + kk * 32 + lg * 8];

  f32x4 o[2][4] = {};
  float Mr[2][4], Lr[2][4];
#pragma unroll
  for (int m = 0; m < 2; ++m)
#pragma unroll
    for (int r = 0; r < 4; ++r) { Mr[m][r] = -1e30f; Lr[m][r] = 0.f; }

  const float cs = 0.18033688f;  // 0.125 * log2(e)

  for (int kt = 0; kt < 2048; kt += 64) {
    // ---- stage K tile [64 kv rows][64 d], swizzled source ----
#pragma unroll
    for (int i = 0; i < 2; ++i) {
      int s = i * 256 + t;
      int row = s >> 3;
      int k2 = (s & 7) ^ (row & 7);
      gload_lds16(&Kh[(size_t)(kt + row) * 1024 + k2 * 8], &Ks[(i * 256 + wv * 64) * 8]);
    }
    // ---- stage V transposed: Vt[d][kv], key = ((d&7)^(d>>3))&7 ----
    {
      int kv0 = (t >> 3) * 2, d0 = (t & 7) * 8;
      u16x8 v0 = *(const u16x8*)&Vh[(size_t)(kt + kv0) * 1024 + d0];
      u16x8 v1 = *(const u16x8*)&Vh[(size_t)(kt + kv0 + 1) * 1024 + d0];
#pragma unroll
      for (int e = 0; e < 8; ++e) {
        int d = d0 + e;
        int key = ((d & 7) ^ (d >> 3)) & 7;
        int idx = d * 64 + (((kv0 >> 3) ^ key) * 8) + (kv0 & 7);
        *(u32*)&Vt[idx] = (u32)v0[e] | ((u32)v1[e] << 16);
      }
    }
    __syncthreads();

    // ---- S = Q K^T (fp32 accum) ----
    f32x4 s4[2][4] = {};
#pragma unroll
    for (int kk = 0; kk < 2; ++kk) {
      bf16x8 kf[4];
#pragma unroll
      for (int n = 0; n < 4; ++n) {
        int row = n * 16 + l15;
        kf[n] = *(const bf16x8*)&Ks[row * 64 + (((kk * 4 + lg) ^ (row & 7)) * 8)];
      }
#pragma unroll
      for (int m = 0; m < 2; ++m)
#pragma unroll
        for (int n = 0; n < 4; ++n)
          s4[m][n] = __builtin_amdgcn_mfma_f32_16x16x32_bf16(qf[m][kk], kf[n], s4[m][n], 0, 0, 0);
    }

    // ---- online softmax (rows live in (lg,r); cols across n and l&15) ----
#pragma unroll
    for (int m = 0; m < 2; ++m) {
#pragma unroll
      for (int r = 0; r < 4; ++r) {
        float mx = fmaxf(fmaxf(s4[m][0][r], s4[m][1][r]),
                         fmaxf(s4[m][2][r], s4[m][3][r]));
#pragma unroll
        for (int sh = 1; sh < 16; sh <<= 1)
          mx = fmaxf(mx, __shfl_xor(mx, sh));
        float Mn = fmaxf(Mr[m][r], mx);
        float co = exp2f((Mr[m][r] - Mn) * cs);
        float rs = 0.f;
#pragma unroll
        for (int n = 0; n < 4; ++n) {
          float pv = exp2f((s4[m][n][r] - Mn) * cs);
          s4[m][n][r] = pv;
          rs += pv;
        }
#pragma unroll
        for (int sh = 1; sh < 16; sh <<= 1)
          rs += __shfl_xor(rs, sh);
        Lr[m][r] = Lr[m][r] * co + rs;
        Mr[m][r] = Mn;
#pragma unroll
        for (int dn = 0; dn < 4; ++dn)
          o[m][dn][r] *= co;
      }
    }

    // ---- write P to per-wave LDS (bf16), key = q&7 ----
#pragma unroll
    for (int m = 0; m < 2; ++m)
#pragma unroll
      for (int r = 0; r < 4; ++r) {
        int q = m * 16 + lg * 4 + r;
        int key = q & 7;
#pragma unroll
        for (int n = 0; n < 4; ++n) {
          int kv = n * 16 + l15;
          int idx = q * 64 + (((kv >> 3) ^ key) * 8) + (kv & 7);
          Pl[wv][idx] = (u16)f2bf(s4[m][n][r]);
        }
      }
    __syncthreads();  // conservative: order P write->read (remove later)

    // ---- O += P V ----
#pragma unroll
    for (int kk = 0; kk < 2; ++kk) {
      bf16x8 pa[2], vf[4];
#pragma unroll
      for (int m = 0; m < 2; ++m) {
        int q = m * 16 + l15;
        pa[m] = *(const bf16x8*)&Pl[wv][q * 64 + (((kk * 4 + lg) ^ (q & 7)) * 8)];
      }
#pragma unroll
      for (int dn = 0; dn < 4; ++dn) {
        int d = dn * 16 + l15;
        int key = ((d & 7) ^ (d >> 3)) & 7;
        vf[dn] = *(const bf16x8*)&Vt[d * 64 + (((kk * 4 + lg) ^ key) * 8)];
      }
#pragma unroll
      for (int m = 0; m < 2; ++m)
#pragma unroll
        for (int dn = 0; dn < 4; ++dn)
          o[m][dn] = __builtin_amdgcn_mfma_f32_16x16x32_bf16(pa[m], vf[dn], o[m][dn], 0, 0, 0);
    }

    __syncthreads();  // protect Ks/Vt before next staging
  }

  // ---- epilogue: normalize and store bf16 ----
#pragma unroll
  for (int m = 0; m < 2; ++m)
#pragma unroll
    for (int r = 0; r < 4; ++r) {
      float inv = 1.f / Lr[m][r];
      int row = q0 + m * 16 + lg * 4 + r;
#pragma unroll
      for (int dn = 0; dn < 4; ++dn)
        AOh[(size_t)row * 1024 + dn * 16 + l15] = (u16)f2bf(o[m][dn][r] * inv);
    }
}

// ---------------------------------------------------------------------------
extern "C" void kernel_launch(void* const* d_in, const int* in_sizes, int n_in,
                              void* d_out, int out_size, void* d_ws, size_t ws_size,
                              hipStream_t stream) {
  const float* x  = (const float*)d_in[0];
  const float* wq = (const float*)d_in[1];
  const float* wk = (const float*)d_in[2];
  const float* wv = (const float*)d_in[3];
  const float* wo = (const float*)d_in[4];

  u16* ws = (u16*)d_ws;
  u16* xb  = ws;                 // 4194304  (x bf16)
  u16* wqb = ws + 4194304;       // 1048576
  u16* wkb = ws + 5242880;
  u16* wvb = ws + 6291456;
  u16* wob = ws + 7340032;
  u16* Qm  = ws + 8388608;       // 4194304
  u16* Km  = ws + 12582912;
  u16* Vm  = ws + 16777216;
  u16* AOm = ws + 20971520;      // end at 25165824 u16 = 48 MiB

  cvt_all<<<4096, 256, 0, stream>>>(x, wq, wk, wv, wo, ws);
  gemm_qkv<<<768, 256, 0, stream>>>(xb, wqb, wkb, wvb, Qm, Km, Vm);
  attn_fwd<<<dim3(16, 32), 256, 0, stream>>>(Qm, Km, Vm, AOm);
  gemm_out<<<256, 256, 0, stream>>>(AOm, wob, (float*)d_out);
}

// Round 4
// 141.631 us; speedup vs baseline: 1.3891x; 1.3891x over previous
//
#include <hip/hip_runtime.h>

using u16 = unsigned short;
using u32 = unsigned int;

typedef __bf16 bf16x8 __attribute__((ext_vector_type(8)));
typedef float  f32x4  __attribute__((ext_vector_type(4)));
typedef float  f32x16 __attribute__((ext_vector_type(16)));
typedef u16    u16x8  __attribute__((ext_vector_type(8)));
typedef u32    u32x4  __attribute__((ext_vector_type(4)));

// fp32 -> bf16 bits, round-to-nearest-even
__device__ __forceinline__ u32 f2bf(float f) {
  u32 u = __builtin_bit_cast(u32, f);
  return (u + 0x7fffu + ((u >> 16) & 1u)) >> 16;
}

// async global->LDS, 16B per lane; LDS dest is wave-uniform base + lane*16
__device__ __forceinline__ void gload_lds16(const u16* g, u16* lds) {
  __builtin_amdgcn_global_load_lds(
      (const __attribute__((address_space(1))) void*)g,
      (__attribute__((address_space(3))) void*)lds, 16, 0, 0);
}

// v_cvt_pk_bf16_f32: low16 = bf16(lo), high16 = bf16(hi)
__device__ __forceinline__ u32 cvtpk(float lo, float hi) {
  u32 r;
  asm("v_cvt_pk_bf16_f32 %0, %1, %2" : "=v"(r) : "v"(lo), "v"(hi));
  return r;
}

// cross-half (lane ^ 32) exchange via known-good wave64 shuffle
__device__ __forceinline__ float xhalf_max(float v) {
  return fmaxf(v, __shfl_xor(v, 32));
}
__device__ __forceinline__ float xhalf_add(float v) {
  return v + __shfl_xor(v, 32);
}

// ---------------------------------------------------------------------------
// fp32 -> bf16 conversion of x (4194304) + Wq/Wk/Wv/Wo (4 x 1048576)
// ---------------------------------------------------------------------------
__global__ __launch_bounds__(256) void cvt_all(
    const float* __restrict__ x,  const float* __restrict__ wq,
    const float* __restrict__ wk, const float* __restrict__ wv,
    const float* __restrict__ wo, u16* __restrict__ out) {
  size_t i = ((size_t)blockIdx.x * 256 + threadIdx.x) * 8;
  const float* src;
  if (i < 4194304) {
    src = x + i;
  } else {
    size_t j = i - 4194304;
    unsigned w = (unsigned)(j >> 20);
    size_t o = j & 1048575;
    src = (w == 0) ? (wq + o) : (w == 1) ? (wk + o) : (w == 2) ? (wv + o) : (wo + o);
  }
  f32x4 a = *(const f32x4*)src;
  f32x4 b = *(const f32x4*)(src + 4);
  u32x4 r;
  r[0] = f2bf(a[0]) | (f2bf(a[1]) << 16);
  r[1] = f2bf(a[2]) | (f2bf(a[3]) << 16);
  r[2] = f2bf(b[0]) | (f2bf(b[1]) << 16);
  r[3] = f2bf(b[2]) | (f2bf(b[3]) << 16);
  *(u32x4*)(out + i) = r;
}

// ---------------------------------------------------------------------------
// C[M,N] = A[M,K] * B[N,K]^T  (unchanged; passed in round 1)
// ---------------------------------------------------------------------------
template <bool F32OUT>
__device__ __forceinline__ void gemm_tile(const u16* __restrict__ A,
                                          const u16* __restrict__ Bm,
                                          void* __restrict__ Cv,
                                          int rowBase, int colBase) {
  __shared__ __align__(16) u16 As[128 * 64];
  __shared__ __align__(16) u16 Bs[128 * 64];

  const int t = threadIdx.x;
  const int lane = t & 63;
  const int wv = t >> 6;
  const int wr = (wv >> 1) * 64;
  const int wc = (wv & 1) * 64;
  const int l15 = lane & 15;
  const int lg = lane >> 4;

  f32x4 acc[4][4] = {};

  for (int kt = 0; kt < 1024; kt += 64) {
#pragma unroll
    for (int i = 0; i < 4; ++i) {
      int s = i * 256 + t;
      int row = s >> 3;
      int k2 = (s & 7) ^ (row & 7);
      const u16* ga = A  + (size_t)(rowBase + row) * 1024 + kt + k2 * 8;
      const u16* gb = Bm + (size_t)(colBase + row) * 1024 + kt + k2 * 8;
      gload_lds16(ga, &As[(i * 256 + wv * 64) * 8]);
      gload_lds16(gb, &Bs[(i * 256 + wv * 64) * 8]);
    }
    __syncthreads();
#pragma unroll
    for (int kk = 0; kk < 2; ++kk) {
      bf16x8 af[4], bfr[4];
#pragma unroll
      for (int m = 0; m < 4; ++m) {
        int row = wr + m * 16 + l15;
        af[m] = *(const bf16x8*)&As[row * 64 + (((kk * 4 + lg) ^ (row & 7)) * 8)];
      }
#pragma unroll
      for (int n = 0; n < 4; ++n) {
        int row = wc + n * 16 + l15;
        bfr[n] = *(const bf16x8*)&Bs[row * 64 + (((kk * 4 + lg) ^ (row & 7)) * 8)];
      }
#pragma unroll
      for (int m = 0; m < 4; ++m)
#pragma unroll
        for (int n = 0; n < 4; ++n)
          acc[m][n] = __builtin_amdgcn_mfma_f32_16x16x32_bf16(af[m], bfr[n], acc[m][n], 0, 0, 0);
    }
    __syncthreads();
  }

#pragma unroll
  for (int m = 0; m < 4; ++m) {
#pragma unroll
    for (int r = 0; r < 4; ++r) {
      int row = rowBase + wr + m * 16 + lg * 4 + r;
#pragma unroll
      for (int n = 0; n < 4; ++n) {
        int col = colBase + wc + n * 16 + l15;
        float v = acc[m][n][r];
        if (F32OUT)
          ((float*)Cv)[(size_t)row * 1024 + col] = v;
        else
          ((u16*)Cv)[(size_t)row * 1024 + col] = (u16)f2bf(v);
      }
    }
  }
}

__global__ __launch_bounds__(256) void gemm_qkv(
    const u16* __restrict__ xb,
    const u16* __restrict__ wq, const u16* __restrict__ wk, const u16* __restrict__ wv,
    u16* __restrict__ Qm, u16* __restrict__ Km, u16* __restrict__ Vm) {
  int bx = blockIdx.x;
  int mat = bx >> 8;
  int rem = bx & 255;
  int bm = rem & 31, bn = rem >> 5;
  const u16* B = (mat == 0) ? wq : (mat == 1) ? wk : wv;
  u16* C = (mat == 0) ? Qm : (mat == 1) ? Km : Vm;
  gemm_tile<false>(xb, B, C, bm * 128, bn * 128);
}

__global__ __launch_bounds__(256) void gemm_out(
    const u16* __restrict__ ao, const u16* __restrict__ wo, float* __restrict__ C) {
  int bm = blockIdx.x & 31, bn = blockIdx.x >> 5;
  gemm_tile<true>(ao, wo, C, bm * 128, bn * 128);
}

// ---------------------------------------------------------------------------
// Flash attention v4: v3 structure (swapped-QK 32x32x16, in-register softmax,
// kv-permutation folded into V^T staging so P repack is pure cvt_pk),
// with the cross-half softmax exchange via __shfl_xor (the v2/v3 plswap
// helpers could be register-coalesced into a self-swap -> wrong max/sum).
// ---------------------------------------------------------------------------
__global__ __launch_bounds__(256, 2) void attn_fwd(
    const u16* __restrict__ Q, const u16* __restrict__ K,
    const u16* __restrict__ V, u16* __restrict__ AO) {
  __shared__ __align__(16) u16 Ks[2][64 * 64];  // [kv][d], 16B-granule XOR swz key=row&7
  __shared__ __align__(16) u16 Vt[2][64 * 64];  // [d][kv-permuted], key=((d&7)^(d>>3))&7

  const int t = threadIdx.x;
  const int lane = t & 63;
  const int wv = t >> 6;
  const int l31 = lane & 31;
  const int hi = lane >> 5;

  const int qb = blockIdx.x;  // 0..15
  const int pr = blockIdx.y;  // 0..31 = (b,h)
  const size_t hb = (size_t)(pr >> 4) * 2048 * 1024 + (size_t)(pr & 15) * 64;
  const u16* Qh = Q + hb;
  const u16* Kh = K + hb;
  const u16* Vh = V + hb;
  u16* AOh = AO + hb;

  const int q0w = qb * 128 + wv * 32;

  // Q fragments (B-operand): col q = l31, k(d) chunk (hi,e) = kk*16 + hi*8 + e
  bf16x8 qf[4];
#pragma unroll
  for (int kk = 0; kk < 4; ++kk)
    qf[kk] = *(const bf16x8*)&Qh[(size_t)(q0w + l31) * 1024 + kk * 16 + hi * 8];

  f32x16 ot[2] = {};          // O^T frags: row d = crow(r,hi)+32*dn, col q = l31
  float Mr = -1e30f, Lr = 0.f;
  const float cs = 0.18033688f;  // 1/8 * log2(e)

  const int kv0 = (t >> 3) * 2, d0 = (t & 7) * 8;
  const int kxor = l31 & 7;
  const int kd0 = (l31 & 7) ^ (l31 >> 3);
  // V^T staging target (kv-permuted to match P's natural crow layout):
  const int vblk = kv0 >> 4;
  const int vloc = kv0 & 15;                       // even
  const int vg   = vblk * 2 + ((vloc >> 2) & 1);   // granule
  const int vj   = (vloc & 3) + ((vloc >> 3) & 1) * 4;

  // ---- prologue: stage tile 0 ----
  {
#pragma unroll
    for (int i = 0; i < 2; ++i) {
      int s = i * 256 + t;
      int row = s >> 3;
      int k2 = (s & 7) ^ (row & 7);
      gload_lds16(&Kh[(size_t)row * 1024 + k2 * 8], &Ks[0][(i * 256 + wv * 64) * 8]);
    }
    u16x8 v0 = *(const u16x8*)&Vh[(size_t)kv0 * 1024 + d0];
    u16x8 v1 = *(const u16x8*)&Vh[(size_t)(kv0 + 1) * 1024 + d0];
#pragma unroll
    for (int e = 0; e < 8; ++e) {
      int d = d0 + e;
      int key = ((d & 7) ^ (d >> 3)) & 7;
      int idx = d * 64 + ((vg ^ key) * 8) + vj;
      *(u32*)&Vt[0][idx] = (u32)v0[e] | ((u32)v1[e] << 16);
    }
  }
  __syncthreads();

  int cur = 0;
  for (int kt = 0; kt < 2048; kt += 64) {
    // ---- issue next-tile prefetch (K direct to LDS, V to regs) ----
    u16x8 pv0, pv1;
    const bool pf = (kt + 64) < 2048;
    if (pf) {
#pragma unroll
      for (int i = 0; i < 2; ++i) {
        int s = i * 256 + t;
        int row = s >> 3;
        int k2 = (s & 7) ^ (row & 7);
        gload_lds16(&Kh[(size_t)(kt + 64 + row) * 1024 + k2 * 8],
                    &Ks[cur ^ 1][(i * 256 + wv * 64) * 8]);
      }
      pv0 = *(const u16x8*)&Vh[(size_t)(kt + 64 + kv0) * 1024 + d0];
      pv1 = *(const u16x8*)&Vh[(size_t)(kt + 64 + kv0 + 1) * 1024 + d0];
    }

    // ---- S^T = K Q^T : rows kv, cols q ----
    const u16* ks = &Ks[cur][0];
    f32x16 sc[2] = {};
#pragma unroll
    for (int kk = 0; kk < 4; ++kk) {
      bf16x8 kf0 = *(const bf16x8*)&ks[l31 * 64 + (((kk * 2 + hi) ^ kxor) * 8)];
      bf16x8 kf1 = *(const bf16x8*)&ks[(32 + l31) * 64 + (((kk * 2 + hi) ^ kxor) * 8)];
      sc[0] = __builtin_amdgcn_mfma_f32_32x32x16_bf16(kf0, qf[kk], sc[0], 0, 0, 0);
      sc[1] = __builtin_amdgcn_mfma_f32_32x32x16_bf16(kf1, qf[kk], sc[1], 0, 0, 0);
    }

    // ---- in-register online softmax (lane owns q=l31; 32 of 64 kv here,
    //      other 32 in partner lane l^32) ----
    float m8[8];
#pragma unroll
    for (int r = 0; r < 8; ++r)
      m8[r] = fmaxf(fmaxf(sc[0][r], sc[0][r + 8]), fmaxf(sc[1][r], sc[1][r + 8]));
    float pm = fmaxf(fmaxf(fmaxf(m8[0], m8[1]), fmaxf(m8[2], m8[3])),
                     fmaxf(fmaxf(m8[4], m8[5]), fmaxf(m8[6], m8[7])));
    pm = xhalf_max(pm);
    float Mn = fmaxf(Mr, pm);
    float co = exp2f((Mr - Mn) * cs);
    Mr = Mn;
#pragma unroll
    for (int fi = 0; fi < 2; ++fi)
#pragma unroll
      for (int r = 0; r < 16; ++r)
        sc[fi][r] = exp2f((sc[fi][r] - Mn) * cs);
    float t8[8];
#pragma unroll
    for (int r = 0; r < 8; ++r)
      t8[r] = (sc[0][r] + sc[0][r + 8]) + (sc[1][r] + sc[1][r + 8]);
    float rs = ((t8[0] + t8[1]) + (t8[2] + t8[3])) +
               ((t8[4] + t8[5]) + (t8[6] + t8[7]));
    rs = xhalf_add(rs);
    Lr = Lr * co + rs;
#pragma unroll
    for (int r = 0; r < 16; ++r) { ot[0][r] *= co; ot[1][r] *= co; }

    // ---- P -> bf16 B-operand frags: straight cvt_pk packs, NO exchange.
    //      pa[kk] slot (hi,e) = P[kv = kk*16 + (e&3)+8*(e>>2)+4*hi], which
    //      matches the permuted V^T staging by construction. ----
    bf16x8 pa[4];
#pragma unroll
    for (int fi = 0; fi < 2; ++fi) {
      u32x4 w0 = {cvtpk(sc[fi][0],  sc[fi][1]),  cvtpk(sc[fi][2],  sc[fi][3]),
                  cvtpk(sc[fi][4],  sc[fi][5]),  cvtpk(sc[fi][6],  sc[fi][7])};
      u32x4 w1 = {cvtpk(sc[fi][8],  sc[fi][9]),  cvtpk(sc[fi][10], sc[fi][11]),
                  cvtpk(sc[fi][12], sc[fi][13]), cvtpk(sc[fi][14], sc[fi][15])};
      pa[2 * fi]     = __builtin_bit_cast(bf16x8, w0);
      pa[2 * fi + 1] = __builtin_bit_cast(bf16x8, w1);
    }

    // ---- O^T += V^T P^T ----
    const u16* vt = &Vt[cur][0];
#pragma unroll
    for (int kk = 0; kk < 4; ++kk) {
      bf16x8 vf0 = *(const bf16x8*)&vt[l31 * 64 + (((kk * 2 + hi) ^ kd0) * 8)];
      bf16x8 vf1 = *(const bf16x8*)&vt[(32 + l31) * 64 + (((kk * 2 + hi) ^ (kd0 ^ 4)) * 8)];
      ot[0] = __builtin_amdgcn_mfma_f32_32x32x16_bf16(vf0, pa[kk], ot[0], 0, 0, 0);
      ot[1] = __builtin_amdgcn_mfma_f32_32x32x16_bf16(vf1, pa[kk], ot[1], 0, 0, 0);
    }

    // ---- land prefetched V into the other buffer ----
    if (pf) {
#pragma unroll
      for (int e = 0; e < 8; ++e) {
        int d = d0 + e;
        int key = ((d & 7) ^ (d >> 3)) & 7;
        int idx = d * 64 + ((vg ^ key) * 8) + vj;
        *(u32*)&Vt[cur ^ 1][idx] = (u32)pv0[e] | ((u32)pv1[e] << 16);
      }
    }
    __syncthreads();
    cur ^= 1;
  }

  // ---- epilogue: normalize, store bf16 pairs (q = l31 per lane) ----
  float inv = 1.f / Lr;
  const size_t qrow = (size_t)(q0w + l31) * 1024;
#pragma unroll
  for (int dn = 0; dn < 2; ++dn)
#pragma unroll
    for (int j = 0; j < 8; ++j) {
      int r = 2 * j;
      int d = 2 * (j & 1) + 8 * (j >> 1) + 4 * hi + 32 * dn;
      u32 w = cvtpk(ot[dn][r] * inv, ot[dn][r + 1] * inv);
      *(u32*)&AOh[qrow + d] = w;
    }
}

// ---------------------------------------------------------------------------
extern "C" void kernel_launch(void* const* d_in, const int* in_sizes, int n_in,
                              void* d_out, int out_size, void* d_ws, size_t ws_size,
                              hipStream_t stream) {
  const float* x  = (const float*)d_in[0];
  const float* wq = (const float*)d_in[1];
  const float* wk = (const float*)d_in[2];
  const float* wv = (const float*)d_in[3];
  const float* wo = (const float*)d_in[4];

  u16* ws = (u16*)d_ws;
  u16* xb  = ws;                 // 4194304  (x bf16)
  u16* wqb = ws + 4194304;       // 1048576
  u16* wkb = ws + 5242880;
  u16* wvb = ws + 6291456;
  u16* wob = ws + 7340032;
  u16* Qm  = ws + 8388608;       // 4194304
  u16* Km  = ws + 12582912;
  u16* Vm  = ws + 16777216;
  u16* AOm = ws + 20971520;      // end at 25165824 u16 = 48 MiB

  cvt_all<<<4096, 256, 0, stream>>>(x, wq, wk, wv, wo, ws);
  gemm_qkv<<<768, 256, 0, stream>>>(xb, wqb, wkb, wvb, Qm, Km, Vm);
  attn_fwd<<<dim3(16, 32), 256, 0, stream>>>(Qm, Km, Vm, AOm);
  gemm_out<<<256, 256, 0, stream>>>(AOm, wob, (float*)d_out);
}